// Round 1
// baseline (182.470 us; speedup 1.0000x reference)
//
#include <hip/hip_runtime.h>
#include <cstdint>

// ---------------------------------------------------------------------------
// QuantumCoherentLayer collapsed:
//   out[b,h] = sum_j w[j] * ( alpha*coh[b,j,h] + (1-alpha)*path_act[b,j,h] )
//   w[j] = (alpha/64) * colsum_j( softmax_rows( cos(phase * J_sym) ) )
//   matmul part = x @ (W_input @ W_eff),  W_eff[h1,h] = sum_j w[j]*Wp[j,h1,h]
// B=2048, D=H=1024, P=8. bf16 MFMA for GEMMs ((1-alpha) crushes the error),
// fp32 for the coherent-state term.
// ---------------------------------------------------------------------------

typedef __attribute__((ext_vector_type(8))) __bf16 bf16x8;
typedef __attribute__((ext_vector_type(4))) float f32x4;

__device__ __forceinline__ unsigned short f32_to_bf16_rne(float f) {
  unsigned int u = __float_as_uint(f);
  u += 0x7fffu + ((u >> 16) & 1u);
  return (unsigned short)(u >> 16);
}

__device__ __forceinline__ void load16_lds(const void* g, void* l) {
  __builtin_amdgcn_global_load_lds(
      (const __attribute__((address_space(1))) void*)g,
      (__attribute__((address_space(3))) void*)(unsigned int)(unsigned long long)l,
      16, 0, 0);
}

// ---------------------------------------------------------------------------
// Kernel 1: scalars. One wave. s[0..7] = w[j]*(1-alpha), s[8..15] = w[j]*alpha
// ---------------------------------------------------------------------------
__global__ void k_scalars(const float* __restrict__ J, const float* __restrict__ t,
                          float* __restrict__ s) {
  const int lane = threadIdx.x;  // 64 threads
  float tv = t[0];
  float alpha = expf(-tv / 51.0f);
  alpha = fminf(fmaxf(alpha, 0.0f), 1.0f);
  float phase = 2.0f * 3.14159265358979323846f * 20.0f * tv / 1000.0f;
  int i = lane >> 3, j = lane & 7;
  float jsym = 0.5f * (J[i * 8 + j] + J[j * 8 + i]);
  float e = expf(cosf(phase * jsym));
  // softmax denominator: sum over j within each row (groups of 8 lanes)
  float rs = e;
  rs += __shfl_xor(rs, 1);
  rs += __shfl_xor(rs, 2);
  rs += __shfl_xor(rs, 4);
  float p = e / rs;
  // column sum over i (lane stride 8)
  float cs = p;
  cs += __shfl_xor(cs, 8);
  cs += __shfl_xor(cs, 16);
  cs += __shfl_xor(cs, 32);
  float w = alpha * (1.0f / 64.0f) * cs;
  if (lane < 8) {                  // lanes 0..7 hold colsum for j=lane
    s[lane] = w * (1.0f - alpha);  // folded into W_eff
    s[8 + lane] = w * alpha;       // for coherent_state term
  }
}

// ---------------------------------------------------------------------------
// Kernel 2: fp32 -> bf16 convert for x [2048x1024] and W_input [1024x1024].
// One float4 -> ushort4 per thread. 524288 + 262144 = 786432 threads.
// ---------------------------------------------------------------------------
__global__ void k_convert(const float* __restrict__ x, const float* __restrict__ win,
                          unsigned short* __restrict__ xb, unsigned short* __restrict__ winb) {
  int idx = blockIdx.x * 256 + threadIdx.x;
  const float4* src;
  unsigned short* dst;
  int off;
  if (idx < 524288) { src = (const float4*)x;   dst = xb;   off = idx; }
  else              { src = (const float4*)win; dst = winb; off = idx - 524288; }
  float4 v = src[off];
  ushort4 o;
  o.x = f32_to_bf16_rne(v.x);
  o.y = f32_to_bf16_rne(v.y);
  o.z = f32_to_bf16_rne(v.z);
  o.w = f32_to_bf16_rne(v.w);
  ((ushort4*)dst)[off] = o;
}

// ---------------------------------------------------------------------------
// Kernel 3: Weff_t[k][h1] = (1-a) * sum_j w[j] * Wp[j][h1][k]   (bf16 out)
// 32x32 tile transpose through LDS; reads are k-contiguous (coalesced).
// block (32,8); grid (32,32): x over k, y over h1.
// ---------------------------------------------------------------------------
__global__ void k_wefft(const float* __restrict__ Wp, const float* __restrict__ s,
                        unsigned short* __restrict__ wefft) {
  __shared__ float lt[32][33];
  const int tx = threadIdx.x;  // k within tile
  const int ty = threadIdx.y;
  const int k0 = blockIdx.x * 32;
  const int h0 = blockIdx.y * 32;
  float wj[8];
#pragma unroll
  for (int j = 0; j < 8; j++) wj[j] = s[j];
  float acc[4] = {0.f, 0.f, 0.f, 0.f};
#pragma unroll
  for (int j = 0; j < 8; j++) {
    const float* base = Wp + (size_t)j * 1024 * 1024;
#pragma unroll
    for (int r = 0; r < 4; r++) {
      int h1 = h0 + ty + 8 * r;
      acc[r] += wj[j] * base[(size_t)h1 * 1024 + k0 + tx];
    }
  }
#pragma unroll
  for (int r = 0; r < 4; r++) lt[ty + 8 * r][tx] = acc[r];  // lt[h1_local][k_local]
  __syncthreads();
#pragma unroll
  for (int r = 0; r < 4; r++) {
    float v = lt[tx][ty + 8 * r];  // (h1_local=tx, k_local=ty+8r)
    wefft[(size_t)(k0 + ty + 8 * r) * 1024 + h0 + tx] = f32_to_bf16_rne(v);
  }
}

// ---------------------------------------------------------------------------
// GEMM: C[m][n] = sum_k A[m][k]*B[n][k], A,B bf16 row-major (k contiguous).
// Block 64x64 (4 waves, each 32x32 via 2x2 of 16x16x32 MFMA). BK=32.
// global_load_lds width-16 staging; XOR swizzle on 16B k-groups vs row to
// reduce ds_read_b128 bank conflicts.
// MAIN=1: out fp32 += sum_p wA[p]*coh[m][p][n].  MAIN=0: out bf16.
// ---------------------------------------------------------------------------
template <int MAIN>
__global__ __launch_bounds__(256) void k_gemm64(
    const unsigned short* __restrict__ A,  // [M][K]
    const unsigned short* __restrict__ B,  // [N][K]
    int K,
    float* __restrict__ outf,              // MAIN: [M][1024]
    unsigned short* __restrict__ outb,     // !MAIN: [M][1024]
    const float* __restrict__ coh,         // MAIN: [M][8][1024]
    const float* __restrict__ s) {
  __shared__ alignas(16) unsigned short As[64 * 32];
  __shared__ alignas(16) unsigned short Bs[64 * 32];
  const int m0 = blockIdx.x * 64;
  const int n0 = blockIdx.y * 64;
  const int tid = threadIdx.x;
  const int wave = tid >> 6;
  const int lane = tid & 63;
  const int quad = lane >> 4;
  const int t16 = lane & 15;

  // staging: wave stages 16 rows of A and 16 rows of B (1KB each)
  const int srow = lane >> 2;                    // row within the wave's 16
  const int sgrp = (lane & 3) ^ (srow & 3);      // swizzled 16B k-group
  const unsigned short* gA = A + (size_t)(m0 + wave * 16 + srow) * K + sgrp * 8;
  const unsigned short* gB = B + (size_t)(n0 + wave * 16 + srow) * K + sgrp * 8;
  unsigned short* lA = As + wave * 512 + lane * 8;
  unsigned short* lB = Bs + wave * 512 + lane * 8;

  const int wm = (wave >> 1) * 32;
  const int wn = (wave & 1) * 32;
  const int ar0 = wm + t16, ar1 = wm + 16 + t16;
  const int br0 = wn + t16, br1 = wn + 16 + t16;
  const unsigned short* pa0 = As + ar0 * 32 + ((quad ^ (ar0 & 3)) * 8);
  const unsigned short* pa1 = As + ar1 * 32 + ((quad ^ (ar1 & 3)) * 8);
  const unsigned short* pb0 = Bs + br0 * 32 + ((quad ^ (br0 & 3)) * 8);
  const unsigned short* pb1 = Bs + br1 * 32 + ((quad ^ (br1 & 3)) * 8);

  f32x4 acc00 = {0.f, 0.f, 0.f, 0.f}, acc01 = acc00, acc10 = acc00, acc11 = acc00;

  for (int kt = 0; kt < K; kt += 32) {
    __syncthreads();
    load16_lds(gA + kt, lA);
    load16_lds(gB + kt, lB);
    __syncthreads();
    bf16x8 a0 = *(const bf16x8*)pa0;
    bf16x8 a1 = *(const bf16x8*)pa1;
    bf16x8 b0 = *(const bf16x8*)pb0;
    bf16x8 b1 = *(const bf16x8*)pb1;
    acc00 = __builtin_amdgcn_mfma_f32_16x16x32_bf16(a0, b0, acc00, 0, 0, 0);
    acc01 = __builtin_amdgcn_mfma_f32_16x16x32_bf16(a0, b1, acc01, 0, 0, 0);
    acc10 = __builtin_amdgcn_mfma_f32_16x16x32_bf16(a1, b0, acc10, 0, 0, 0);
    acc11 = __builtin_amdgcn_mfma_f32_16x16x32_bf16(a1, b1, acc11, 0, 0, 0);
  }

  // epilogue: C row = quad*4 + reg, col = t16 (m89-verified layout)
  f32x4 accv[2][2] = {{acc00, acc01}, {acc10, acc11}};
  if constexpr (MAIN != 0) {
    float wA[8];
#pragma unroll
    for (int p = 0; p < 8; p++) wA[p] = s[8 + p];
#pragma unroll
    for (int i = 0; i < 2; i++) {
#pragma unroll
      for (int r = 0; r < 4; r++) {
        int m = m0 + wm + i * 16 + quad * 4 + r;
        const float* cb = coh + (size_t)m * 8192;
#pragma unroll
        for (int j = 0; j < 2; j++) {
          int n = n0 + wn + j * 16 + t16;
          float c = 0.f;
#pragma unroll
          for (int p = 0; p < 8; p++) c += wA[p] * cb[p * 1024 + n];
          outf[(size_t)m * 1024 + n] = accv[i][j][r] + c;
        }
      }
    }
  } else {
#pragma unroll
    for (int i = 0; i < 2; i++) {
#pragma unroll
      for (int r = 0; r < 4; r++) {
        int m = m0 + wm + i * 16 + quad * 4 + r;
#pragma unroll
        for (int j = 0; j < 2; j++) {
          int n = n0 + wn + j * 16 + t16;
          outb[(size_t)m * 1024 + n] = f32_to_bf16_rne(accv[i][j][r]);
        }
      }
    }
  }
}

// ---------------------------------------------------------------------------
extern "C" void kernel_launch(void* const* d_in, const int* in_sizes, int n_in,
                              void* d_out, int out_size, void* d_ws, size_t ws_size,
                              hipStream_t stream) {
  const float* x   = (const float*)d_in[0];  // [2048,1024]
  const float* win = (const float*)d_in[1];  // [1024,1024]
  const float* wp  = (const float*)d_in[2];  // [8,1024,1024]
  const float* J   = (const float*)d_in[3];  // [8,8]
  const float* coh = (const float*)d_in[4];  // [2048,8,1024]
  const float* t   = (const float*)d_in[5];  // [1]
  float* out = (float*)d_out;                // [2048,1024] fp32

  char* ws = (char*)d_ws;
  float* s              = (float*)ws;                                  // 16 floats
  unsigned short* xb    = (unsigned short*)(ws + 64);                  // 4 MB
  unsigned short* winb  = (unsigned short*)(ws + 64 + 4u * 1024 * 1024);   // 2 MB
  unsigned short* wefft = (unsigned short*)(ws + 64 + 6u * 1024 * 1024);   // 2 MB
  unsigned short* wct   = (unsigned short*)(ws + 64 + 8u * 1024 * 1024);   // 2 MB

  k_scalars<<<1, 64, 0, stream>>>(J, t, s);
  k_convert<<<3072, 256, 0, stream>>>(x, win, xb, winb);
  k_wefft<<<dim3(32, 32), dim3(32, 8), 0, stream>>>(wp, s, wefft);
  // Wct[h][d] = sum_h1 Weff_t[h][h1] * Win[d][h1]   (= (1-a)*(Win@Weff)^T)
  k_gemm64<0><<<dim3(16, 16), 256, 0, stream>>>(wefft, winb, 1024, nullptr, wct,
                                                nullptr, s);
  // out[b][h] = sum_d x[b][d]*Wct[h][d] + sum_p wA[p]*coh[b][p][h]
  k_gemm64<1><<<dim3(32, 16), 256, 0, stream>>>(xb, wct, 1024, out, nullptr,
                                                coh, s);
}